// Round 7
// baseline (1564.368 us; speedup 1.0000x reference)
//
#include <hip/hip_runtime.h>
#include <hip/hip_bf16.h>

// B=256, L=512, E=256, V=50000, C=5
#define EDIM 256
#define TWO_E 512
#define CDIM 5
#define NNODES 1023

__device__ __forceinline__ void project_one(const float* __restrict__ row,
                                            const float* __restrict__ P,
                                            const float* __restrict__ pb,
                                            float* __restrict__ out,
                                            long long obase, int lane) {
    float s0 = 0.f, s1 = 0.f, s2 = 0.f, s3 = 0.f, s4 = 0.f;
#pragma unroll
    for (int k = 0; k < 4; ++k) {
        int pe = lane + 64 * k;
        float v = row[pe];
        s0 = fmaf(v, P[0 * EDIM + pe], s0);
        s1 = fmaf(v, P[1 * EDIM + pe], s1);
        s2 = fmaf(v, P[2 * EDIM + pe], s2);
        s3 = fmaf(v, P[3 * EDIM + pe], s3);
        s4 = fmaf(v, P[4 * EDIM + pe], s4);
    }
#pragma unroll
    for (int off = 32; off; off >>= 1) {
        s0 += __shfl_xor(s0, off);
        s1 += __shfl_xor(s1, off);
        s2 += __shfl_xor(s2, off);
        s3 += __shfl_xor(s3, off);
        s4 += __shfl_xor(s4, off);
    }
    if (lane == 0) {
        out[obase + 0] = s0 + pb[0];
        out[obase + 1] = s1 + pb[1];
        out[obase + 2] = s2 + pb[2];
        out[obase + 3] = s3 + pb[3];
        out[obase + 4] = s4 + pb[4];
    }
}

// ME=2 x K-split compose: thread t handles e-rows {e, e+128} (e = t&127) over
// K-half (t>>7). Halves the ds_read_b128 count vs 1-e-per-thread full-K:
// each 16B child read now feeds 8 FMAs. Partials from the hi K-half go
// through a scratch overlay at LDS rows [16, 16+NPAR) (dead child data).
template<int NPAR>
__device__ __forceinline__ void do_level(float* lds, const float* __restrict__ W,
                                         float b0, float b1, int tid, int lane, int wid,
                                         const float* __restrict__ P,
                                         const float* __restrict__ pb,
                                         float* __restrict__ out, long long obase) {
    const int e = tid & 127;
    const int half = tid >> 7;  // 0: f in [0,256)  1: f in [256,512)
    float acc0[NPAR], acc1[NPAR];
#pragma unroll
    for (int p = 0; p < NPAR; ++p) { acc0[p] = 0.f; acc1[p] = 0.f; }
    const float4* Wa = (const float4*)W + (long long)e * 128 + half * 64;
    const float4* Wb = (const float4*)W + (long long)(e + 128) * 128 + half * 64;
    const float4* ch = (const float4*)lds + half * 64;
    for (int f4 = 0; f4 < 64; ++f4) {
        float4 wva = Wa[f4];
        float4 wvb = Wb[f4];
#pragma unroll
        for (int p = 0; p < NPAR; ++p) {
            float4 cv = ch[p * 128 + f4];  // wave-uniform broadcast, conflict-free
            acc0[p] = fmaf(wva.x, cv.x, acc0[p]);
            acc0[p] = fmaf(wva.y, cv.y, acc0[p]);
            acc0[p] = fmaf(wva.z, cv.z, acc0[p]);
            acc0[p] = fmaf(wva.w, cv.w, acc0[p]);
            acc1[p] = fmaf(wvb.x, cv.x, acc1[p]);
            acc1[p] = fmaf(wvb.y, cv.y, acc1[p]);
            acc1[p] = fmaf(wvb.z, cv.z, acc1[p]);
            acc1[p] = fmaf(wvb.w, cv.w, acc1[p]);
        }
    }
    __syncthreads();  // child reads done -> rows reusable
    float* scratch = lds + 16 * EDIM;  // rows [16, 16+NPAR): dead child data
    if (half) {
#pragma unroll
        for (int p = 0; p < NPAR; ++p) {
            scratch[p * EDIM + e] = acc0[p];
            scratch[p * EDIM + e + 128] = acc1[p];
        }
    }
    __syncthreads();
    if (!half) {
#pragma unroll
        for (int p = 0; p < NPAR; ++p) {
            lds[p * EDIM + e] = fmaxf(acc0[p] + scratch[p * EDIM + e] + b0, 0.f);
            lds[p * EDIM + e + 128] = fmaxf(acc1[p] + scratch[p * EDIM + e + 128] + b1, 0.f);
        }
    }
    __syncthreads();  // parents complete
    for (int r = wid; r < NPAR; r += 4)
        project_one(lds + r * EDIM, P, pb, out, obase + (long long)r * CDIM, lane);
    // no trailing barrier: next level's post-K-loop barrier orders scratch writes
    // after all projection reads (projection-only-reads parents; K-loop only reads).
}

// One block = one 32-leaf subtree. Leaves + levels 1..5 compose+projection.
__global__ __launch_bounds__(256) void k_tree_lo(
    const int* __restrict__ words, const float* __restrict__ emb,
    const float* __restrict__ W, const float* __restrict__ bvec,
    const float* __restrict__ P, const float* __restrict__ pb,
    float* __restrict__ out, float* __restrict__ h5) {
    __shared__ alignas(16) float lds[32 * EDIM];  // 32 KiB (children + scratch overlay)
    const int tid = threadIdx.x, lane = tid & 63, wid = tid >> 6;
    const long long gp0 = (long long)blockIdx.x * 16;  // level-1 flat base (b*256 + n1)
    const long long leaf0 = 2 * gp0;                   // leaf flat base (b*512 + pos)
    const long long bI = gp0 >> 8;
    const int g = (int)(gp0 & 255);

    for (int r = 0; r < 32; ++r) {
        int wd = words[leaf0 + r];
        lds[r * EDIM + tid] = fmaxf(emb[(long long)wd * EDIM + tid], 0.f);
    }
    __syncthreads();

    const long long base = bI * NNODES;
    for (int r = wid; r < 32; r += 4)
        project_one(lds + r * EDIM, P, pb, out, (base + 2 * g + r) * CDIM, lane);

    const float b0 = bvec[tid & 127];
    const float b1 = bvec[(tid & 127) + 128];
    do_level<16>(lds, W, b0, b1, tid, lane, wid, P, pb, out, (base + 512 + g) * CDIM);
    do_level<8>(lds, W, b0, b1, tid, lane, wid, P, pb, out, (base + 768 + (g >> 1)) * CDIM);
    do_level<4>(lds, W, b0, b1, tid, lane, wid, P, pb, out, (base + 896 + (g >> 2)) * CDIM);
    do_level<2>(lds, W, b0, b1, tid, lane, wid, P, pb, out, (base + 960 + (g >> 3)) * CDIM);
    do_level<1>(lds, W, b0, b1, tid, lane, wid, P, pb, out, (base + 992 + (g >> 4)) * CDIM);

    h5[((bI << 4) + (g >> 4)) * EDIM + tid] = lds[tid];  // f32 L5 row
}

// One block per batch: levels 6..9 from the 16 L5 rows.
__global__ __launch_bounds__(256) void k_tree_hi(
    const float* __restrict__ h5, const float* __restrict__ W,
    const float* __restrict__ bvec, const float* __restrict__ P,
    const float* __restrict__ pb, float* __restrict__ out) {
    __shared__ alignas(16) float lds[32 * EDIM];  // child rows [0,16) + scratch [16,24)
    const int tid = threadIdx.x, lane = tid & 63, wid = tid >> 6;
    const long long b = blockIdx.x;
    for (int i = tid; i < 16 * EDIM; i += 256)
        lds[i] = h5[b * 16 * EDIM + i];
    __syncthreads();

    const float b0 = bvec[tid & 127];
    const float b1 = bvec[(tid & 127) + 128];
    const long long base = b * NNODES;
    do_level<8>(lds, W, b0, b1, tid, lane, wid, P, pb, out, (base + 1008) * CDIM);
    do_level<4>(lds, W, b0, b1, tid, lane, wid, P, pb, out, (base + 1016) * CDIM);
    do_level<2>(lds, W, b0, b1, tid, lane, wid, P, pb, out, (base + 1020) * CDIM);
    do_level<1>(lds, W, b0, b1, tid, lane, wid, P, pb, out, (base + 1022) * CDIM);
}

extern "C" void kernel_launch(void* const* d_in, const int* in_sizes, int n_in,
                              void* d_out, int out_size, void* d_ws, size_t ws_size,
                              hipStream_t stream) {
    const int* words = (const int*)d_in[0];
    const float* emb = (const float*)d_in[1];
    const float* W = (const float*)d_in[2];
    const float* bv = (const float*)d_in[3];
    const float* P = (const float*)d_in[4];
    const float* pb = (const float*)d_in[5];
    float* out = (float*)d_out;  // f32 output (reference dtype)

    float* h5 = (float*)d_ws;  // 4096 x 256 f32 = 4 MiB

    k_tree_lo<<<4096, 256, 0, stream>>>(words, emb, W, bv, P, pb, out, h5);
    k_tree_hi<<<256, 256, 0, stream>>>(h5, W, bv, P, pb, out);
}

// Round 8
// 736.766 us; speedup vs baseline: 2.1233x; 2.1233x over previous
//
#include <hip/hip_runtime.h>
#include <hip/hip_bf16.h>

// B=256, L=512, E=256, V=50000, C=5
#define EDIM 256
#define TWO_E 512
#define CDIM 5
#define NNODES 1023

// Permute W (f32 [256][512], row-major e-major) into Wp[f4][e][4]:
// Wp4[f4*256 + e] = W[e][4*f4 .. 4*f4+3].  In the compose K-loop, lane l
// (thread e = base+l) then reads Wp4[f4*256 + e] -> 16B per lane, wave =
// contiguous 1KB: perfectly coalesced (vs 2KB-strided scatter before).
__global__ __launch_bounds__(256) void k_prep(const float* __restrict__ W,
                                              float4* __restrict__ Wp4) {
    const int f4 = blockIdx.x;    // [0,128)
    const int e = threadIdx.x;    // [0,256)
    const float4* W4 = (const float4*)W;
    Wp4[f4 * 256 + e] = W4[(long long)e * 128 + f4];
}

__device__ __forceinline__ void project_one(const float* __restrict__ row,
                                            const float* __restrict__ P,
                                            const float* __restrict__ pb,
                                            float* __restrict__ out,
                                            long long obase, int lane) {
    float s0 = 0.f, s1 = 0.f, s2 = 0.f, s3 = 0.f, s4 = 0.f;
#pragma unroll
    for (int k = 0; k < 4; ++k) {
        int pe = lane + 64 * k;
        float v = row[pe];
        s0 = fmaf(v, P[0 * EDIM + pe], s0);
        s1 = fmaf(v, P[1 * EDIM + pe], s1);
        s2 = fmaf(v, P[2 * EDIM + pe], s2);
        s3 = fmaf(v, P[3 * EDIM + pe], s3);
        s4 = fmaf(v, P[4 * EDIM + pe], s4);
    }
#pragma unroll
    for (int off = 32; off; off >>= 1) {
        s0 += __shfl_xor(s0, off);
        s1 += __shfl_xor(s1, off);
        s2 += __shfl_xor(s2, off);
        s3 += __shfl_xor(s3, off);
        s4 += __shfl_xor(s4, off);
    }
    if (lane == 0) {
        out[obase + 0] = s0 + pb[0];
        out[obase + 1] = s1 + pb[1];
        out[obase + 2] = s2 + pb[2];
        out[obase + 3] = s3 + pb[3];
        out[obase + 4] = s4 + pb[4];
    }
}

// ME=2 x K-split compose with COALESCED W (Wp layout). Thread t handles
// e-rows {e, e+128} (e = t&127) over K-half (t>>7).
template<int NPAR>
__device__ __forceinline__ void do_level(float* lds, const float4* __restrict__ Wp4,
                                         float b0, float b1, int tid, int lane, int wid,
                                         const float* __restrict__ P,
                                         const float* __restrict__ pb,
                                         float* __restrict__ out, long long obase) {
    const int e = tid & 127;
    const int half = tid >> 7;  // 0: f in [0,256)  1: f in [256,512)
    float acc0[NPAR], acc1[NPAR];
#pragma unroll
    for (int p = 0; p < NPAR; ++p) { acc0[p] = 0.f; acc1[p] = 0.f; }
    const float4* ch = (const float4*)lds + half * 64;
    const float4* Wrow = Wp4 + (long long)(half * 64) * 256;  // f4-major
    for (int f4 = 0; f4 < 64; ++f4) {
        float4 wva = Wrow[f4 * 256 + e];          // coalesced: wave = 1KB contiguous
        float4 wvb = Wrow[f4 * 256 + e + 128];    // coalesced
#pragma unroll
        for (int p = 0; p < NPAR; ++p) {
            float4 cv = ch[p * 128 + f4];  // wave-uniform broadcast
            acc0[p] = fmaf(wva.x, cv.x, acc0[p]);
            acc0[p] = fmaf(wva.y, cv.y, acc0[p]);
            acc0[p] = fmaf(wva.z, cv.z, acc0[p]);
            acc0[p] = fmaf(wva.w, cv.w, acc0[p]);
            acc1[p] = fmaf(wvb.x, cv.x, acc1[p]);
            acc1[p] = fmaf(wvb.y, cv.y, acc1[p]);
            acc1[p] = fmaf(wvb.z, cv.z, acc1[p]);
            acc1[p] = fmaf(wvb.w, cv.w, acc1[p]);
        }
    }
    __syncthreads();  // child reads done -> rows reusable
    float* scratch = lds + 16 * EDIM;  // rows [16, 16+NPAR): dead child data
    if (half) {
#pragma unroll
        for (int p = 0; p < NPAR; ++p) {
            scratch[p * EDIM + e] = acc0[p];
            scratch[p * EDIM + e + 128] = acc1[p];
        }
    }
    __syncthreads();
    if (!half) {
#pragma unroll
        for (int p = 0; p < NPAR; ++p) {
            lds[p * EDIM + e] = fmaxf(acc0[p] + scratch[p * EDIM + e] + b0, 0.f);
            lds[p * EDIM + e + 128] = fmaxf(acc1[p] + scratch[p * EDIM + e + 128] + b1, 0.f);
        }
    }
    __syncthreads();  // parents complete
    for (int r = wid; r < NPAR; r += 4)
        project_one(lds + r * EDIM, P, pb, out, obase + (long long)r * CDIM, lane);
}

// One block = one 32-leaf subtree. Leaves + levels 1..5 compose+projection.
__global__ __launch_bounds__(256) void k_tree_lo(
    const int* __restrict__ words, const float* __restrict__ emb,
    const float4* __restrict__ Wp4, const float* __restrict__ bvec,
    const float* __restrict__ P, const float* __restrict__ pb,
    float* __restrict__ out, float* __restrict__ h5) {
    __shared__ alignas(16) float lds[32 * EDIM];  // 32 KiB (children + scratch overlay)
    const int tid = threadIdx.x, lane = tid & 63, wid = tid >> 6;
    const long long gp0 = (long long)blockIdx.x * 16;  // level-1 flat base (b*256 + n1)
    const long long leaf0 = 2 * gp0;                   // leaf flat base (b*512 + pos)
    const long long bI = gp0 >> 8;
    const int g = (int)(gp0 & 255);

    for (int r = 0; r < 32; ++r) {
        int wd = words[leaf0 + r];
        lds[r * EDIM + tid] = fmaxf(emb[(long long)wd * EDIM + tid], 0.f);
    }
    __syncthreads();

    const long long base = bI * NNODES;
    for (int r = wid; r < 32; r += 4)
        project_one(lds + r * EDIM, P, pb, out, (base + 2 * g + r) * CDIM, lane);

    const float b0 = bvec[tid & 127];
    const float b1 = bvec[(tid & 127) + 128];
    do_level<16>(lds, Wp4, b0, b1, tid, lane, wid, P, pb, out, (base + 512 + g) * CDIM);
    do_level<8>(lds, Wp4, b0, b1, tid, lane, wid, P, pb, out, (base + 768 + (g >> 1)) * CDIM);
    do_level<4>(lds, Wp4, b0, b1, tid, lane, wid, P, pb, out, (base + 896 + (g >> 2)) * CDIM);
    do_level<2>(lds, Wp4, b0, b1, tid, lane, wid, P, pb, out, (base + 960 + (g >> 3)) * CDIM);
    do_level<1>(lds, Wp4, b0, b1, tid, lane, wid, P, pb, out, (base + 992 + (g >> 4)) * CDIM);

    h5[((bI << 4) + (g >> 4)) * EDIM + tid] = lds[tid];  // f32 L5 row
}

// One block per batch: levels 6..9 from the 16 L5 rows.
__global__ __launch_bounds__(256) void k_tree_hi(
    const float* __restrict__ h5, const float4* __restrict__ Wp4,
    const float* __restrict__ bvec, const float* __restrict__ P,
    const float* __restrict__ pb, float* __restrict__ out) {
    __shared__ alignas(16) float lds[32 * EDIM];  // child rows [0,16) + scratch [16,24)
    const int tid = threadIdx.x, lane = tid & 63, wid = tid >> 6;
    const long long b = blockIdx.x;
    for (int i = tid; i < 16 * EDIM; i += 256)
        lds[i] = h5[b * 16 * EDIM + i];
    __syncthreads();

    const float b0 = bvec[tid & 127];
    const float b1 = bvec[(tid & 127) + 128];
    const long long base = b * NNODES;
    do_level<8>(lds, Wp4, b0, b1, tid, lane, wid, P, pb, out, (base + 1008) * CDIM);
    do_level<4>(lds, Wp4, b0, b1, tid, lane, wid, P, pb, out, (base + 1016) * CDIM);
    do_level<2>(lds, Wp4, b0, b1, tid, lane, wid, P, pb, out, (base + 1020) * CDIM);
    do_level<1>(lds, Wp4, b0, b1, tid, lane, wid, P, pb, out, (base + 1022) * CDIM);
}

extern "C" void kernel_launch(void* const* d_in, const int* in_sizes, int n_in,
                              void* d_out, int out_size, void* d_ws, size_t ws_size,
                              hipStream_t stream) {
    const int* words = (const int*)d_in[0];
    const float* emb = (const float*)d_in[1];
    const float* W = (const float*)d_in[2];
    const float* bv = (const float*)d_in[3];
    const float* P = (const float*)d_in[4];
    const float* pb = (const float*)d_in[5];
    float* out = (float*)d_out;  // f32 output (reference dtype)

    // d_ws layout: Wp (512 KiB) | h5 (4 MiB)
    float4* Wp4 = (float4*)d_ws;
    float* h5 = (float*)d_ws + 131072;

    k_prep<<<128, 256, 0, stream>>>(W, Wp4);
    k_tree_lo<<<4096, 256, 0, stream>>>(words, emb, Wp4, bv, P, pb, out, h5);
    k_tree_hi<<<256, 256, 0, stream>>>(h5, Wp4, bv, P, pb, out);
}

// Round 9
// 491.760 us; speedup vs baseline: 3.1812x; 1.4982x over previous
//
#include <hip/hip_runtime.h>
#include <hip/hip_bf16.h>

// B=256, L=512, E=256, V=50000, C=5
#define EDIM 256
#define TWO_E 512
#define CDIM 5
#define NNODES 1023

typedef short bf16x8 __attribute__((ext_vector_type(8)));
typedef float f32x4 __attribute__((ext_vector_type(4)));

__device__ __forceinline__ unsigned short f2bf(float v) {
    return __builtin_bit_cast(unsigned short, __float2bfloat16(v));
}
__device__ __forceinline__ float bf2f(unsigned short u) {
    return __bfloat162float(__builtin_bit_cast(__hip_bfloat16, u));
}
// pack f32 -> (hi<<16)|lo split-bf16
__device__ __forceinline__ unsigned packhl(float v) {
    unsigned short hb = f2bf(v);
    unsigned short lb = f2bf(v - bf2f(hb));
    return ((unsigned)hb << 16) | lb;
}
__device__ __forceinline__ float unpackhl(unsigned u) {
    return bf2f((unsigned short)(u >> 16)) + bf2f((unsigned short)(u & 0xffff));
}

__device__ __forceinline__ void project_one(const float* __restrict__ row,
                                            const float* __restrict__ P,
                                            const float* __restrict__ pb,
                                            float* __restrict__ out,
                                            long long obase, int lane) {
    float s0 = 0.f, s1 = 0.f, s2 = 0.f, s3 = 0.f, s4 = 0.f;
#pragma unroll
    for (int k = 0; k < 4; ++k) {
        int pe = lane + 64 * k;
        float v = row[pe];
        s0 = fmaf(v, P[0 * EDIM + pe], s0);
        s1 = fmaf(v, P[1 * EDIM + pe], s1);
        s2 = fmaf(v, P[2 * EDIM + pe], s2);
        s3 = fmaf(v, P[3 * EDIM + pe], s3);
        s4 = fmaf(v, P[4 * EDIM + pe], s4);
    }
#pragma unroll
    for (int off = 32; off; off >>= 1) {
        s0 += __shfl_xor(s0, off);
        s1 += __shfl_xor(s1, off);
        s2 += __shfl_xor(s2, off);
        s3 += __shfl_xor(s3, off);
        s4 += __shfl_xor(s4, off);
    }
    if (lane == 0) {
        out[obase + 0] = s0 + pb[0];
        out[obase + 1] = s1 + pb[1];
        out[obase + 2] = s2 + pb[2];
        out[obase + 3] = s3 + pb[3];
        out[obase + 4] = s4 + pb[4];
    }
}

// ---------------- prep kernels ----------------

// W (f32 [e=256][f=512]) -> MFMA B-fragment order, split bf16 hi/lo.
// frag index = (kstep*16 + ntile)*64 + lane; lane supplies B[k][n]:
// n = ntile*16 + (lane&15), k = kstep*32 + (lane>>4)*8 + j  (j=0..7).
__global__ __launch_bounds__(256) void k_prep_wm(const float* __restrict__ W,
                                                 bf16x8* __restrict__ Wm_hi,
                                                 bf16x8* __restrict__ Wm_lo) {
    const int st = blockIdx.x * 256 + threadIdx.x;  // [0, 16384)
    const int ks = st >> 10, nt = (st >> 6) & 15, l = st & 63;
    const int e = nt * 16 + (l & 15);
    const int f0 = ks * 32 + (l >> 4) * 8;
    bf16x8 h8, l8;
#pragma unroll
    for (int j = 0; j < 8; ++j) {
        float v = W[(long long)e * TWO_E + f0 + j];
        unsigned short hb = f2bf(v);
        h8[j] = (short)hb;
        l8[j] = (short)f2bf(v - bf2f(hb));
    }
    Wm_hi[st] = h8;
    Wm_lo[st] = l8;
}

// f32 coalesced W for the VALU tail path: Wp4[f4*256+e] = W[e][4f4..]
__global__ __launch_bounds__(256) void k_prep(const float* __restrict__ W,
                                              float4* __restrict__ Wp4) {
    const int f4 = blockIdx.x;
    const int e = threadIdx.x;
    Wp4[f4 * 256 + e] = ((const float4*)W)[(long long)e * 128 + f4];
}

// ---------------- leaf projection ----------------
__global__ __launch_bounds__(256) void k_leafproj(
    const int* __restrict__ words, const float* __restrict__ emb,
    const float* __restrict__ P, const float* __restrict__ pb,
    float* __restrict__ out) {
    __shared__ alignas(16) float lds[32 * EDIM];
    const int tid = threadIdx.x, lane = tid & 63, wid = tid >> 6;
    const long long leaf0 = (long long)blockIdx.x * 32;
    for (int r = 0; r < 32; ++r) {
        int wd = words[leaf0 + r];
        lds[r * EDIM + tid] = fmaxf(emb[(long long)wd * EDIM + tid], 0.f);
    }
    __syncthreads();
    for (int r = wid; r < 32; r += 4) {
        long long leaf = leaf0 + r;
        long long bI = leaf >> 9, pos = leaf & 511;
        project_one(lds + r * EDIM, P, pb, out, (bI * NNODES + pos) * CDIM, lane);
    }
}

// ---------------- MFMA level kernel (levels 1..5) ----------------
// Block: 64 parents (BM=64), full N=256, K=512 in two halves (left/right child).
// A (children) in LDS as bf16 hi/lo, XOR-swizzled; B (W) streamed from global
// in MFMA frag layout. Split-bf16: D += Ah*Bh + Ah*Bl + Al*Bh (f32 acc).
template<bool LV1>
__global__ __launch_bounds__(256) void k_level(
    const unsigned* __restrict__ h_in, const int* __restrict__ words,
    const float* __restrict__ emb, const bf16x8* __restrict__ Wm_hi,
    const bf16x8* __restrict__ Wm_lo, const float* __restrict__ bvec,
    const float* __restrict__ P, const float* __restrict__ pb,
    float* __restrict__ out, unsigned* __restrict__ h_out,
    int npar_shift, int node_off) {
    __shared__ alignas(16) char alds[65536];  // A hi [0,32K) lo [32K,64K); later h f32
    __shared__ float s_bias[256];
    const int tid = threadIdx.x, lane = tid & 63, wid = tid >> 6;
    const long long mb = (long long)blockIdx.x * 64;

    s_bias[tid] = bvec[tid];

    f32x4 acc[4][4];
#pragma unroll
    for (int mt = 0; mt < 4; ++mt)
#pragma unroll
        for (int a = 0; a < 4; ++a) acc[mt][a] = (f32x4){0.f, 0.f, 0.f, 0.f};

    for (int half = 0; half < 2; ++half) {
        // ---- stage A: rows p[0,64), local f q[0,256) from child row 2*(mb+p)+half
        for (int i = 0; i < 32; ++i) {
            int linear = i * 256 + tid;        // [0, 8192)
            int p = linear >> 7;
            int qp = (linear & 127) << 1;      // even q
            long long crow = 2 * (mb + p) + half;
            unsigned hp, lp;
            if constexpr (LV1) {
                int wd = words[crow];
                float2 vv = *(const float2*)&emb[(long long)wd * EDIM + qp];
                float v0 = fmaxf(vv.x, 0.f), v1 = fmaxf(vv.y, 0.f);
                unsigned short h0 = f2bf(v0), h1 = f2bf(v1);
                unsigned short l0 = f2bf(v0 - bf2f(h0)), l1 = f2bf(v1 - bf2f(h1));
                hp = (unsigned)h0 | ((unsigned)h1 << 16);
                lp = (unsigned)l0 | ((unsigned)l1 << 16);
            } else {
                unsigned u0 = h_in[crow * 256 + qp];
                unsigned u1 = h_in[crow * 256 + qp + 1];
                hp = (u0 >> 16) | (u1 & 0xffff0000u);
                lp = (u0 & 0xffffu) | (u1 << 16);
            }
            int addr = (p * 512 + qp * 2) ^ ((p & 7) << 4);  // T2 swizzle
            *(unsigned*)(alds + addr) = hp;
            *(unsigned*)(alds + 32768 + addr) = lp;
        }
        __syncthreads();

        // ---- MFMA k-loop: 8 k-steps of 32 over this half
        const int nt0 = wid * 4;
        for (int ks = 0; ks < 8; ++ks) {
            const int ksg = half * 8 + ks;
            bf16x8 wh[4], wl[4];
#pragma unroll
            for (int a = 0; a < 4; ++a) {
                int frag = (ksg * 16 + nt0 + a) * 64 + lane;
                wh[a] = Wm_hi[frag];
                wl[a] = Wm_lo[frag];
            }
#pragma unroll
            for (int mt = 0; mt < 4; ++mt) {
                int p = mt * 16 + (lane & 15);
                int byte = (p * 512 + ks * 64 + (lane >> 4) * 16) ^ ((p & 7) << 4);
                bf16x8 ah = *(const bf16x8*)(alds + byte);
                bf16x8 al = *(const bf16x8*)(alds + 32768 + byte);
#pragma unroll
                for (int a = 0; a < 4; ++a) {
                    acc[mt][a] = __builtin_amdgcn_mfma_f32_16x16x32_bf16(ah, wh[a], acc[mt][a], 0, 0, 0);
                    acc[mt][a] = __builtin_amdgcn_mfma_f32_16x16x32_bf16(ah, wl[a], acc[mt][a], 0, 0, 0);
                    acc[mt][a] = __builtin_amdgcn_mfma_f32_16x16x32_bf16(al, wh[a], acc[mt][a], 0, 0, 0);
                }
            }
        }
        __syncthreads();  // k-loop reads done before restage / epilogue overlay
    }

    // ---- epilogue: acc -> h (relu+bias) into LDS f32 overlay
    float* h_lds = (float*)alds;  // [64][256]
    const int nt0 = wid * 4;
#pragma unroll
    for (int mt = 0; mt < 4; ++mt)
#pragma unroll
        for (int a = 0; a < 4; ++a)
#pragma unroll
            for (int r = 0; r < 4; ++r) {
                int p = mt * 16 + (lane >> 4) * 4 + r;  // D row = M (m89 layout)
                int e = (nt0 + a) * 16 + (lane & 15);   // D col = N
                h_lds[p * 256 + e] = fmaxf(acc[mt][a][r] + s_bias[e], 0.f);
            }
    __syncthreads();

    // packed global write (coalesced)
    for (int i = 0; i < 64; ++i) {
        int linear = i * 256 + tid;
        h_out[mb * 256 + linear] = packhl(h_lds[linear]);
    }
    // projection of the 64 parents
    const int npar_mask = (1 << npar_shift) - 1;
    for (int r = wid; r < 64; r += 4) {
        long long gp = mb + r;
        long long bI = gp >> npar_shift;
        long long n = gp & npar_mask;
        project_one(h_lds + r * 256, P, pb, out, (bI * NNODES + node_off + n) * CDIM, lane);
    }
}

// ---------------- VALU tail (levels 6..9) + fallback path ----------------

template<int NPAR>
__device__ __forceinline__ void do_level(float* lds, const float4* __restrict__ Wp4,
                                         float b0, float b1, int tid, int lane, int wid,
                                         const float* __restrict__ P,
                                         const float* __restrict__ pb,
                                         float* __restrict__ out, long long obase) {
    const int e = tid & 127;
    const int half = tid >> 7;
    float acc0[NPAR], acc1[NPAR];
#pragma unroll
    for (int p = 0; p < NPAR; ++p) { acc0[p] = 0.f; acc1[p] = 0.f; }
    const float4* ch = (const float4*)lds + half * 64;
    const float4* Wrow = Wp4 + (long long)(half * 64) * 256;
    for (int f4 = 0; f4 < 64; ++f4) {
        float4 wva = Wrow[f4 * 256 + e];
        float4 wvb = Wrow[f4 * 256 + e + 128];
#pragma unroll
        for (int p = 0; p < NPAR; ++p) {
            float4 cv = ch[p * 128 + f4];
            acc0[p] = fmaf(wva.x, cv.x, acc0[p]);
            acc0[p] = fmaf(wva.y, cv.y, acc0[p]);
            acc0[p] = fmaf(wva.z, cv.z, acc0[p]);
            acc0[p] = fmaf(wva.w, cv.w, acc0[p]);
            acc1[p] = fmaf(wvb.x, cv.x, acc1[p]);
            acc1[p] = fmaf(wvb.y, cv.y, acc1[p]);
            acc1[p] = fmaf(wvb.z, cv.z, acc1[p]);
            acc1[p] = fmaf(wvb.w, cv.w, acc1[p]);
        }
    }
    __syncthreads();
    float* scratch = lds + 16 * EDIM;
    if (half) {
#pragma unroll
        for (int p = 0; p < NPAR; ++p) {
            scratch[p * EDIM + e] = acc0[p];
            scratch[p * EDIM + e + 128] = acc1[p];
        }
    }
    __syncthreads();
    if (!half) {
#pragma unroll
        for (int p = 0; p < NPAR; ++p) {
            lds[p * EDIM + e] = fmaxf(acc0[p] + scratch[p * EDIM + e] + b0, 0.f);
            lds[p * EDIM + e + 128] = fmaxf(acc1[p] + scratch[p * EDIM + e + 128] + b1, 0.f);
        }
    }
    __syncthreads();
    for (int r = wid; r < NPAR; r += 4)
        project_one(lds + r * EDIM, P, pb, out, obase + (long long)r * CDIM, lane);
}

template<bool PACKED>
__global__ __launch_bounds__(256) void k_tree_hi(
    const void* __restrict__ h5v, const float4* __restrict__ Wp4,
    const float* __restrict__ bvec, const float* __restrict__ P,
    const float* __restrict__ pb, float* __restrict__ out) {
    __shared__ alignas(16) float lds[32 * EDIM];
    const int tid = threadIdx.x, lane = tid & 63, wid = tid >> 6;
    const long long b = blockIdx.x;
    for (int i = tid; i < 16 * EDIM; i += 256) {
        if constexpr (PACKED)
            lds[i] = unpackhl(((const unsigned*)h5v)[b * 16 * EDIM + i]);
        else
            lds[i] = ((const float*)h5v)[b * 16 * EDIM + i];
    }
    __syncthreads();
    const float b0 = bvec[tid & 127];
    const float b1 = bvec[(tid & 127) + 128];
    const long long base = b * NNODES;
    do_level<8>(lds, Wp4, b0, b1, tid, lane, wid, P, pb, out, (base + 1008) * CDIM);
    do_level<4>(lds, Wp4, b0, b1, tid, lane, wid, P, pb, out, (base + 1016) * CDIM);
    do_level<2>(lds, Wp4, b0, b1, tid, lane, wid, P, pb, out, (base + 1020) * CDIM);
    do_level<1>(lds, Wp4, b0, b1, tid, lane, wid, P, pb, out, (base + 1022) * CDIM);
}

// fallback (proven round-8): full VALU subtree kernel
__global__ __launch_bounds__(256) void k_tree_lo_fb(
    const int* __restrict__ words, const float* __restrict__ emb,
    const float4* __restrict__ Wp4, const float* __restrict__ bvec,
    const float* __restrict__ P, const float* __restrict__ pb,
    float* __restrict__ out, float* __restrict__ h5) {
    __shared__ alignas(16) float lds[32 * EDIM];
    const int tid = threadIdx.x, lane = tid & 63, wid = tid >> 6;
    const long long gp0 = (long long)blockIdx.x * 16;
    const long long leaf0 = 2 * gp0;
    const long long bI = gp0 >> 8;
    const int g = (int)(gp0 & 255);
    for (int r = 0; r < 32; ++r) {
        int wd = words[leaf0 + r];
        lds[r * EDIM + tid] = fmaxf(emb[(long long)wd * EDIM + tid], 0.f);
    }
    __syncthreads();
    const long long base = bI * NNODES;
    for (int r = wid; r < 32; r += 4)
        project_one(lds + r * EDIM, P, pb, out, (base + 2 * g + r) * CDIM, lane);
    const float b0 = bvec[tid & 127];
    const float b1 = bvec[(tid & 127) + 128];
    do_level<16>(lds, Wp4, b0, b1, tid, lane, wid, P, pb, out, (base + 512 + g) * CDIM);
    do_level<8>(lds, Wp4, b0, b1, tid, lane, wid, P, pb, out, (base + 768 + (g >> 1)) * CDIM);
    do_level<4>(lds, Wp4, b0, b1, tid, lane, wid, P, pb, out, (base + 896 + (g >> 2)) * CDIM);
    do_level<2>(lds, Wp4, b0, b1, tid, lane, wid, P, pb, out, (base + 960 + (g >> 3)) * CDIM);
    do_level<1>(lds, Wp4, b0, b1, tid, lane, wid, P, pb, out, (base + 992 + (g >> 4)) * CDIM);
    h5[((bI << 4) + (g >> 4)) * EDIM + tid] = lds[tid];
}

extern "C" void kernel_launch(void* const* d_in, const int* in_sizes, int n_in,
                              void* d_out, int out_size, void* d_ws, size_t ws_size,
                              hipStream_t stream) {
    const int* words = (const int*)d_in[0];
    const float* emb = (const float*)d_in[1];
    const float* W = (const float*)d_in[2];
    const float* bv = (const float*)d_in[3];
    const float* P = (const float*)d_in[4];
    const float* pb = (const float*)d_in[5];
    float* out = (float*)d_out;

    const size_t NEED = 1048576ULL + 67108864ULL + 33554432ULL;  // 1M prep + 64M + 32M
    if (ws_size >= NEED) {
        bf16x8* Wm_hi = (bf16x8*)d_ws;                               // 256 KiB
        bf16x8* Wm_lo = (bf16x8*)((char*)d_ws + 262144);             // 256 KiB
        float4* Wp4 = (float4*)((char*)d_ws + 524288);               // 512 KiB
        unsigned* bufA = (unsigned*)((char*)d_ws + 1048576);         // 64 MiB
        unsigned* bufB = (unsigned*)((char*)d_ws + 1048576 + 67108864);  // 32 MiB

        k_prep_wm<<<64, 256, 0, stream>>>(W, Wm_hi, Wm_lo);
        k_prep<<<128, 256, 0, stream>>>(W, Wp4);
        k_leafproj<<<4096, 256, 0, stream>>>(words, emb, P, pb, out);
        // levels 1..5: Mtot = 65536,32768,16384,8192,4096 -> /64 blocks
        k_level<true><<<1024, 256, 0, stream>>>(nullptr, words, emb, Wm_hi, Wm_lo,
                                                bv, P, pb, out, bufA, 8, 512);
        k_level<false><<<512, 256, 0, stream>>>(bufA, words, emb, Wm_hi, Wm_lo,
                                                bv, P, pb, out, bufB, 7, 768);
        k_level<false><<<256, 256, 0, stream>>>(bufB, words, emb, Wm_hi, Wm_lo,
                                                bv, P, pb, out, bufA, 6, 896);
        k_level<false><<<128, 256, 0, stream>>>(bufA, words, emb, Wm_hi, Wm_lo,
                                                bv, P, pb, out, bufB, 5, 960);
        k_level<false><<<64, 256, 0, stream>>>(bufB, words, emb, Wm_hi, Wm_lo,
                                               bv, P, pb, out, bufA, 4, 992);
        k_tree_hi<true><<<256, 256, 0, stream>>>(bufA, Wp4, bv, P, pb, out);
    } else {
        // proven round-8 path (needs 4.5 MiB)
        float4* Wp4 = (float4*)d_ws;
        float* h5 = (float*)d_ws + 131072;
        k_prep<<<128, 256, 0, stream>>>(W, Wp4);
        k_tree_lo_fb<<<4096, 256, 0, stream>>>(words, emb, Wp4, bv, P, pb, out, h5);
        k_tree_hi<false><<<256, 256, 0, stream>>>(h5, Wp4, bv, P, pb, out);
    }
}